// Round 2
// 242.409 us; speedup vs baseline: 1.0768x; 1.0768x over previous
//
#include <hip/hip_runtime.h>
#include <cstddef>

// HMM forward-backward posterior. Emission terms are state-independent scalars
// per (b,t); they and the batch dim cancel in the per-t state normalization,
// so gamma[b,t,i] == gamma[t,i]. Only the emission-free recursions
// A_t = A_{t-1} (x) M, B_t = M (x) B_{t+1} (log-matmul) matter.
// Three-level chunking: 4096 = 16*16*16. Squarings give M^16, M^256; level-0
// scan (15 steps, M^256) gives 16 super-boundaries; level-1 (16 blocks, 15
// steps, M^16) gives 256 boundaries; level-2 (256 blocks, 15 steps, M) fills
// all t and emits gamma directly.
//
// Round-2 structure: 11 launches (was 14).
//  - prep_col/prep_row kernels eliminated: scan blocks self-prep the
//    exp-rescaled operand into registers straight from the log matrix
//    (alpha lanes read columns - coalesced; beta lanes read rows - L2-hot).
//    Same fmax/exp order as the old preps -> bit-identical.
//  - level-2 scan and gamma fused: one block per 16-chunk runs alpha (half 0)
//    and beta (half 1) chains into LDS, then normalizes + broadcasts out.
//    Deletes the 4 MiB A_t/B_t round-trip and one launch boundary.
// (Round-1 cooperative mega-fusion failed at the LAUNCH level: output stayed
//  memset-0 => hipLaunchCooperativeKernel doesn't execute under this
//  harness's capture. Reverted to plain launches.)

constexpr int NS = 128;
constexpr int TT = 4096;
constexpr int NB = 64;
constexpr int LVL = 16;   // chunk length at every level

// workspace offsets (floats)
constexpr int OFF_P0   = 0;
constexpr int OFF_P1   = 16384;
constexpr int OFF_P16  = 32768;   // M^16 (log)
constexpr int OFF_P256 = 49152;   // M^256 (log)
constexpr int OFF_AB1  = 65536;   // 16  x128 alpha boundaries (t=256c)
constexpr int OFF_BB1  = 67584;   // 16  x128 beta  boundaries (t=256c+255)
constexpr int OFF_AB2  = 69632;   // 256 x128 alpha boundaries (t=16d)
constexpr int OFF_BB2  = 102400;  // 256 x128 beta  boundaries (t=16d+15)
// total 135,168 floats ~ 0.53 MiB

__device__ __forceinline__ float wredmax(float v) {
#pragma unroll
  for (int off = 32; off; off >>= 1) v = fmaxf(v, __shfl_xor(v, off, 64));
  return v;
}
__device__ __forceinline__ float wredsum(float v) {
#pragma unroll
  for (int off = 32; off; off >>= 1) v += __shfl_xor(v, off, 64);
  return v;
}

// One log-matvec step; E column in registers, w broadcast via LDS.
// Barriers sync the whole block; in 256-thread blocks both halves run this
// in lockstep (same trip counts), so barrier counts always match.
__device__ __forceinline__ float step128(float x, const float* __restrict__ Ereg,
                                         float cm, float* xs, float* wsm, int lane) {
  xs[lane] = x;
  __syncthreads();
  float ref = xs[0];                 // any per-t constant cancels in final norm
  float w = __expf(x - ref);
  wsm[lane] = w;
  __syncthreads();
  float acc = 0.f;
  const float4* w4 = (const float4*)wsm;
#pragma unroll
  for (int j = 0; j < 32; ++j) {     // 32 broadcast b128 loads + 128 reg FMAs
    float4 wv = w4[j];
    acc += wv.x * Ereg[4 * j] + wv.y * Ereg[4 * j + 1] +
           wv.z * Ereg[4 * j + 2] + wv.w * Ereg[4 * j + 3];
  }
  return __logf(fmaxf(acc, 1e-37f)) + cm;
}

// Log-matmul squaring P = A (x) A. One block per output row; lane i holds
// exp(A[:,i]-colmax_i) in 128 VGPRs; row weights broadcast via LDS.
// (verbatim from the proven 261us version)
__global__ __launch_bounds__(128, 1) void sq_log(const float* __restrict__ A,
                                                 float* __restrict__ P) {
  __shared__ float wsm[NS];
  __shared__ float red[2];
  int i = threadIdx.x;
  int row = blockIdx.x;
  float Ereg[NS];
  float c = -1e30f;
#pragma unroll
  for (int j = 0; j < NS; ++j) { float v = A[j * NS + i]; Ereg[j] = v; c = fmaxf(c, v); }
#pragma unroll
  for (int j = 0; j < NS; ++j) Ereg[j] = __expf(Ereg[j] - c);
  float xr = A[row * NS + i];
  float m = wredmax(xr);
  if ((i & 63) == 0) red[i >> 6] = m;
  __syncthreads();
  float rm = fmaxf(red[0], red[1]);
  wsm[i] = __expf(xr - rm);
  __syncthreads();
  float acc = 0.f;
  const float4* w4 = (const float4*)wsm;
#pragma unroll
  for (int j = 0; j < 32; ++j) {
    float4 wv = w4[j];
    acc += wv.x * Ereg[4 * j] + wv.y * Ereg[4 * j + 1] +
           wv.z * Ereg[4 * j + 2] + wv.w * Ereg[4 * j + 3];
  }
  P[row * NS + i] = __logf(fmaxf(acc, 1e-37f)) + rm + c;
}

// Self-prep: build the exp-rescaled operand for one chain direction directly
// from the log matrix. half 0 (alpha): lane i holds exp(M[j][i]-colmax_i)
// (column reads, coalesced across lanes). half 1 (beta): lane i holds
// exp(M[i][j]-rowmax_i) (row reads, L2-hot). Same fmax order (j=0..127) and
// exp args as the old prep kernels -> bit-identical values.
__device__ __forceinline__ float selfprep(const float* __restrict__ M, int lane,
                                          int half, float* Ereg) {
  float c = -1e30f;
  if (half == 0) {
#pragma unroll
    for (int j = 0; j < NS; ++j) { float v = M[j * NS + lane]; Ereg[j] = v; c = fmaxf(c, v); }
  } else {
#pragma unroll
    for (int j = 0; j < NS; ++j) { float v = M[lane * NS + j]; Ereg[j] = v; c = fmaxf(c, v); }
  }
#pragma unroll
  for (int j = 0; j < NS; ++j) Ereg[j] = __expf(Ereg[j] - c);
  return c;
}

// Middle scan level: one block per chunk; half 0 runs the alpha chain
// forward, half 1 the beta chain backward (same chunk index). Boundaries
// written to global for the next level. inB==nullptr -> beta starts at 0.
__global__ __launch_bounds__(256, 2) void scan_mid(
    const float* __restrict__ M, const float* __restrict__ inA,
    const float* __restrict__ inB, float* __restrict__ outA,
    float* __restrict__ outB) {
  __shared__ float xs[2][NS];
  __shared__ float wsm[2][NS];
  int tid = threadIdx.x;
  int lane = tid & 127;
  int half = tid >> 7;
  float Ereg[NS];
  float cm = selfprep(M, lane, half, Ereg);
  int c = blockIdx.x;
  float x;
  float* o;
  int s, ds;
  if (half == 0) {
    x = inA[(size_t)c * NS + lane];
    o = outA + (size_t)c * LVL * NS;
    s = 0; ds = 1;
  } else {
    x = inB ? inB[(size_t)c * NS + lane] : 0.f;
    o = outB + (size_t)c * LVL * NS;
    s = LVL - 1; ds = -1;
  }
  o[s * NS + lane] = x;
  for (int k = 1; k < LVL; ++k) {
    x = step128(x, Ereg, cm, xs[half], wsm[half], lane);
    s += ds;
    o[s * NS + lane] = x;
  }
}

// Final level fused with gamma: block c covers t = 16c..16c+15. Alpha and
// beta chains (with M itself) go to LDS; then per-t normalize and broadcast
// the 128-state posterior to all 64 batches.
__global__ __launch_bounds__(256, 2) void scan_fin(
    const float* __restrict__ M, const float* __restrict__ inA,
    const float* __restrict__ inB, float* __restrict__ out) {
  __shared__ float xs[2][NS];
  __shared__ float wsm[2][NS];
  __shared__ float av[LVL][NS];
  __shared__ float bv[LVL][NS];
  __shared__ float red[8];
  __shared__ __align__(16) float g[NS];
  int tid = threadIdx.x;
  int lane = tid & 127;
  int half = tid >> 7;
  int wv = tid >> 6;
  float Ereg[NS];
  float cm = selfprep(M, lane, half, Ereg);
  int c = blockIdx.x;
  if (half == 0) {
    float x = inA[(size_t)c * NS + lane];
    av[0][lane] = x;
    for (int s = 1; s < LVL; ++s) {
      x = step128(x, Ereg, cm, xs[0], wsm[0], lane);
      av[s][lane] = x;
    }
  } else {
    float x = inB[(size_t)c * NS + lane];
    bv[LVL - 1][lane] = x;
    for (int s = LVL - 2; s >= 0; --s) {
      x = step128(x, Ereg, cm, xs[1], wsm[1], lane);
      bv[s][lane] = x;
    }
  }
  __syncthreads();
  // gamma for the 16 t's of this chunk (reduction code verbatim from the
  // proven gamma_out; av/bv now come from LDS instead of global A_t/B_t).
  for (int s2 = 0; s2 < LVL; ++s2) {
    int tt = c * LVL + s2;
    float sv = -1e30f;
    if (tid < NS) sv = av[s2][tid] + bv[s2][tid];
    float mloc = wredmax(sv);
    if ((tid & 63) == 0) red[wv] = mloc;
    __syncthreads();
    float Mx = fmaxf(fmaxf(red[0], red[1]), fmaxf(red[2], red[3]));
    float p = (tid < NS) ? __expf(sv - Mx) : 0.f;
    float sum = wredsum(p);
    if ((tid & 63) == 0) red[4 + wv] = sum;
    __syncthreads();
    float lse = __logf(red[4] + red[5] + red[6] + red[7]) + Mx;
    if (tid < NS) g[tid] = sv - lse;
    __syncthreads();
    const float4* g4 = (const float4*)g;
    float4* o4 = (float4*)out;
    int q = tid & 31;
    int b0 = tid >> 5;
    float4 val = g4[q];
    for (int b = b0; b < NB; b += 8) {
      o4[((size_t)b * TT + tt) * (NS / 4) + q] = val;
    }
    // no trailing barrier needed: next iteration's red/g writes are ordered
    // behind this iteration's reads by the two reduction barriers above.
  }
}

extern "C" void kernel_launch(void* const* d_in, const int* in_sizes, int n_in,
                              void* d_out, int out_size, void* d_ws, size_t ws_size,
                              hipStream_t stream) {
  (void)in_sizes; (void)n_in; (void)out_size; (void)ws_size;
  const float* pi = (const float*)d_in[1];
  const float* Tm = (const float*)d_in[2];
  float* ws = (float*)d_ws;
  float* out = (float*)d_out;

  float* P0 = ws + OFF_P0;
  float* P1 = ws + OFF_P1;
  float* P16 = ws + OFF_P16;
  float* P256 = ws + OFF_P256;

  // M^2..M^256 by repeated squaring; keep M^16 and M^256.
  sq_log<<<128, 128, 0, stream>>>(Tm, P0);     // M^2
  sq_log<<<128, 128, 0, stream>>>(P0, P1);     // M^4
  sq_log<<<128, 128, 0, stream>>>(P1, P0);     // M^8
  sq_log<<<128, 128, 0, stream>>>(P0, P16);    // M^16
  sq_log<<<128, 128, 0, stream>>>(P16, P0);    // M^32
  sq_log<<<128, 128, 0, stream>>>(P0, P1);     // M^64
  sq_log<<<128, 128, 0, stream>>>(P1, P0);     // M^128
  sq_log<<<128, 128, 0, stream>>>(P0, P256);   // M^256

  // level 0: 1 chunk, M^256 -> 16 super-boundaries each direction
  scan_mid<<<1, 256, 0, stream>>>(P256, pi, nullptr,
                                  ws + OFF_AB1, ws + OFF_BB1);
  // level 1: 16 chunks, M^16 -> 256 boundaries
  scan_mid<<<16, 256, 0, stream>>>(P16, ws + OFF_AB1, ws + OFF_BB1,
                                   ws + OFF_AB2, ws + OFF_BB2);
  // level 2 + gamma: 256 chunks, M -> gamma for all t, broadcast to batches
  scan_fin<<<256, 256, 0, stream>>>(Tm, ws + OFF_AB2, ws + OFF_BB2, out);
}